// Round 1
// baseline (684.596 us; speedup 1.0000x reference)
//
#include <hip/hip_runtime.h>
#include <math.h>

#define FRAME_LEN 512
#define HOP       256
#define NFREQ     257
#define NBATCH    64
#define NSAMP     160000
#define TFRAMES   624          // (160000-512)/256 + 1
#define EPS       1.1920928955078125e-07f

#define BM 64                  // frames per tile
#define BF 32                  // freq bins per tile
#define BK 64                  // K chunk
#define PAD 4

// ---------------------------------------------------------------- tables ----
__global__ void gen_tables(float* __restrict__ Wc, float* __restrict__ Ws) {
    int f = blockIdx.x;                       // 0..256
    for (int n = threadIdx.x; n < FRAME_LEN; n += blockDim.x) {
        float w = 0.5f * (1.0f - cosf(2.0f * (float)M_PI * (float)n / (float)FRAME_LEN));
        int r = (f * n) & (FRAME_LEN - 1);    // exact integer angle reduction
        float ang = (float)r * (2.0f * (float)M_PI / (float)FRAME_LEN);
        float s, c;
        sincosf(ang, &s, &c);
        Wc[f * FRAME_LEN + n] = c * w;        // real kernel
        Ws[f * FRAME_LEN + n] = s * w;        // i = +sin*w (i = -Ki, Ki = -sin*w)
    }
}

// ------------------------------------------------------------- stft + mag ---
__global__ __launch_bounds__(256) void stft_mag(
    const float* __restrict__ x, const float* __restrict__ Wc,
    const float* __restrict__ Ws, float* __restrict__ mag)
{
    __shared__ float As[BM][BK + PAD];
    __shared__ float Bc[BF][BK + PAD];
    __shared__ float Bs[BF][BK + PAD];

    const int tileM = blockIdx.x;             // 0..623
    const int tileF = blockIdx.y;             // 0..8
    const int tid = threadIdx.x;
    const int tx = tid & 15;                  // t-group (16)
    const int ty = tid >> 4;                  // f-group (16)

    float accr[4][2] = {{0.f,0.f},{0.f,0.f},{0.f,0.f},{0.f,0.f}};
    float acci[4][2] = {{0.f,0.f},{0.f,0.f},{0.f,0.f},{0.f,0.f}};

    for (int k0 = 0; k0 < FRAME_LEN; k0 += BK) {
        // ---- stage A: 64 frames x 64 samples (float4, coalesced 256B/row)
        #pragma unroll
        for (int i = 0; i < 4; i++) {
            int row = ty + 16 * i;
            int m = tileM * BM + row;         // m < 39936 always (624*64 exact)
            int b = m / TFRAMES;
            int t = m - b * TFRAMES;
            const float4 v = *(const float4*)(x + (size_t)b * NSAMP + t * HOP + k0 + tx * 4);
            *(float4*)&As[row][tx * 4] = v;
        }
        // ---- stage B: 32 bins x 64 samples of cos & sin tables
        #pragma unroll
        for (int i = 0; i < 2; i++) {
            int row = ty + 16 * i;
            int f = tileF * BF + row;
            float4 vc = make_float4(0.f, 0.f, 0.f, 0.f);
            float4 vs = vc;
            if (f < NFREQ) {
                vc = *(const float4*)(Wc + f * FRAME_LEN + k0 + tx * 4);
                vs = *(const float4*)(Ws + f * FRAME_LEN + k0 + tx * 4);
            }
            *(float4*)&Bc[row][tx * 4] = vc;
            *(float4*)&Bs[row][tx * 4] = vs;
        }
        __syncthreads();

        // ---- compute: each thread 4 t (tx+16j) x 2 f (2ty+c), r & i dots
        #pragma unroll
        for (int kk = 0; kk < BK; kk += 4) {
            float4 a[4], bc[2], bs[2];
            #pragma unroll
            for (int j = 0; j < 4; j++) a[j] = *(const float4*)&As[tx + 16 * j][kk];
            #pragma unroll
            for (int c = 0; c < 2; c++) {
                bc[c] = *(const float4*)&Bc[2 * ty + c][kk];
                bs[c] = *(const float4*)&Bs[2 * ty + c][kk];
            }
            #pragma unroll
            for (int j = 0; j < 4; j++) {
                #pragma unroll
                for (int c = 0; c < 2; c++) {
                    accr[j][c] += a[j].x * bc[c].x + a[j].y * bc[c].y
                                + a[j].z * bc[c].z + a[j].w * bc[c].w;
                    acci[j][c] += a[j].x * bs[c].x + a[j].y * bs[c].y
                                + a[j].z * bs[c].z + a[j].w * bs[c].w;
                }
            }
        }
        __syncthreads();
    }

    // ---- epilogue: mag[b][f][t] = sqrt(r^2 + i^2)
    #pragma unroll
    for (int j = 0; j < 4; j++) {
        int m = tileM * BM + tx + 16 * j;
        int b = m / TFRAMES;
        int t = m - b * TFRAMES;
        #pragma unroll
        for (int c = 0; c < 2; c++) {
            int f = tileF * BF + 2 * ty + c;
            if (f < NFREQ) {
                float r = accr[j][c], im = acci[j][c];
                mag[((size_t)b * NFREQ + f) * TFRAMES + t] = sqrtf(r * r + im * im);
            }
        }
    }
}

// ------------------------------------------------------------- normalize ----
__global__ __launch_bounds__(256) void normalize(const float* __restrict__ mag,
                                                 float* __restrict__ feat)
{
    __shared__ float red[8];
    const int row = blockIdx.x;               // b*NFREQ + f
    const float* m = mag + (size_t)row * TFRAMES;
    const int tid = threadIdx.x;
    const int lane = tid & 63;
    const int w = tid >> 6;

    float v[3];
    float sum = 0.f;
    #pragma unroll
    for (int i = 0; i < 3; i++) {
        int t = tid + i * 256;
        v[i] = (t < TFRAMES) ? fmaxf(m[t], EPS) : 0.f;
        sum += v[i];
    }
    // block reduce sum
    #pragma unroll
    for (int off = 32; off > 0; off >>= 1) sum += __shfl_down(sum, off, 64);
    if (lane == 0) red[w] = sum;
    __syncthreads();
    float total = red[0] + red[1] + red[2] + red[3];
    float mean = total * (1.0f / (float)TFRAMES);

    float ssd = 0.f;
    #pragma unroll
    for (int i = 0; i < 3; i++) {
        int t = tid + i * 256;
        if (t < TFRAMES) { float d = v[i] - mean; ssd += d * d; }
    }
    __syncthreads();                          // red reads done before reuse
    #pragma unroll
    for (int off = 32; off > 0; off >>= 1) ssd += __shfl_down(ssd, off, 64);
    if (lane == 0) red[w] = ssd;
    __syncthreads();
    float tssd = red[0] + red[1] + red[2] + red[3];
    float stdv = sqrtf(tssd * (1.0f / (float)(TFRAMES - 1)));
    float inv = 1.0f / (stdv + EPS);

    #pragma unroll
    for (int i = 0; i < 3; i++) {
        int t = tid + i * 256;
        if (t < TFRAMES) feat[(size_t)row * TFRAMES + t] = (v[i] - mean) * inv;
    }
}

// ---------------------------------------------------------------- launch ----
extern "C" void kernel_launch(void* const* d_in, const int* in_sizes, int n_in,
                              void* d_out, int out_size, void* d_ws, size_t ws_size,
                              hipStream_t stream) {
    const float* x = (const float*)d_in[0];
    float* Wc = (float*)d_ws;                         // 257*512 f32
    float* Ws = Wc + NFREQ * FRAME_LEN;               // 257*512 f32
    float* mag = (float*)d_out;                       // [64][257][624]
    float* feat = mag + (size_t)NBATCH * NFREQ * TFRAMES;

    gen_tables<<<NFREQ, 256, 0, stream>>>(Wc, Ws);

    dim3 grid2(TFRAMES * NBATCH / BM, (NFREQ + BF - 1) / BF);   // 624 x 9
    stft_mag<<<grid2, 256, 0, stream>>>(x, Wc, Ws, mag);

    normalize<<<NBATCH * NFREQ, 256, 0, stream>>>(mag, feat);
}

// Round 2
// 95.772 us; speedup vs baseline: 7.1482x; 7.1482x over previous
//
#include <hip/hip_runtime.h>
#include <math.h>

#define FRAME_LEN 512
#define HOP       256
#define NFREQ     257
#define NFREQ_PAD 288
#define NBATCH    64
#define NSAMP     160000
#define TFRAMES   624
#define EPS       1.1920928955078125e-07f

#define MT 128                 // frames per tile
#define FT 32                  // freq bins per tile
#define BK 64                  // K chunk per stage

typedef __attribute__((ext_vector_type(8))) short short8;   // 8 bf16 (4 VGPRs)
typedef __attribute__((ext_vector_type(4))) float f32x4;    // MFMA acc

static __device__ __forceinline__ unsigned int f2bf(float f) {
    unsigned int u = __float_as_uint(f);
    return (u + 0x7fffu + ((u >> 16) & 1u)) >> 16;          // RNE to bf16
}
static __device__ __forceinline__ uint4 pack8(float4 a, float4 b) {
    uint4 r;
    r.x = f2bf(a.x) | (f2bf(a.y) << 16);
    r.y = f2bf(a.z) | (f2bf(a.w) << 16);
    r.z = f2bf(b.x) | (f2bf(b.y) << 16);
    r.w = f2bf(b.z) | (f2bf(b.w) << 16);
    return r;
}

// ---------------------------------------------------------------- tables ----
// bf16 DFT kernels, padded to 288 rows (rows >=257 zeroed).
__global__ void gen_tables(unsigned short* __restrict__ Wc,
                           unsigned short* __restrict__ Ws) {
    int f = blockIdx.x;                         // 0..287
    for (int n = threadIdx.x; n < FRAME_LEN; n += 256) {
        unsigned short c = 0, s = 0;
        if (f < NFREQ) {
            float w = 0.5f * (1.0f - cosf(2.0f * (float)M_PI * (float)n / (float)FRAME_LEN));
            int r = (f * n) & (FRAME_LEN - 1);
            float ang = (float)r * (2.0f * (float)M_PI / (float)FRAME_LEN);
            float sv, cv;
            sincosf(ang, &sv, &cv);
            c = (unsigned short)f2bf(cv * w);   // real kernel
            s = (unsigned short)f2bf(sv * w);   // i = +sin*w
        }
        Wc[f * FRAME_LEN + n] = c;
        Ws[f * FRAME_LEN + n] = s;
    }
}

// ------------------------------------------------------ stft via bf16 MFMA --
__global__ __launch_bounds__(256) void stft_mfma(
    const float* __restrict__ x, const unsigned short* __restrict__ Wc,
    const unsigned short* __restrict__ Ws, float* __restrict__ mag)
{
    __shared__ unsigned short As[MT][BK];       // 16 KB, XOR-swizzled chunks
    __shared__ unsigned short Bs[2][FT][BK];    // 8 KB (cos, sin)

    const int tid = threadIdx.x;
    const int tileM = blockIdx.x;               // 0..311
    const int tileF = blockIdx.y;               // 0..8
    const int wid = tid >> 6;
    const int lane = tid & 63;
    const int lrow = lane & 15;                 // D col / frag row
    const int lhi = lane >> 4;                  // 0..3

    f32x4 accr[2][2] = {};
    f32x4 acci[2][2] = {};

    const int ar0 = tid >> 2;                   // A stage: row 0..63 (+64)
    const int aseg = tid & 3;                   // 16 f32 per seg
    const int br = tid >> 3;                    // B stage: row 0..31
    const int bseg = tid & 7;                   // 8 bf16 per seg

    for (int k0 = 0; k0 < FRAME_LEN; k0 += BK) {
        __syncthreads();
        // ---- stage A: 128 rows x 64 k, f32 -> bf16 in flight
        #pragma unroll
        for (int i = 0; i < 2; i++) {
            int r = ar0 + 64 * i;
            int m = tileM * MT + r;
            int b = m / TFRAMES;
            int t = m - b * TFRAMES;
            const float4* src = (const float4*)(x + (size_t)b * NSAMP + t * HOP + k0 + aseg * 16);
            float4 v0 = src[0], v1 = src[1], v2 = src[2], v3 = src[3];
            uint4 p0 = pack8(v0, v1);
            uint4 p1 = pack8(v2, v3);
            int c0 = (aseg * 2) ^ (r & 7);
            int c1 = (aseg * 2 + 1) ^ (r & 7);
            *(uint4*)&As[r][c0 * 8] = p0;
            *(uint4*)&As[r][c1 * 8] = p1;
        }
        // ---- stage B: 32 rows x 64 k of cos & sin (already bf16)
        {
            int fglob = tileF * FT + br;        // < 288
            uint4 vc = *(const uint4*)(Wc + fglob * FRAME_LEN + k0 + bseg * 8);
            uint4 vs = *(const uint4*)(Ws + fglob * FRAME_LEN + k0 + bseg * 8);
            int c = bseg ^ (br & 7);
            *(uint4*)&Bs[0][br][c * 8] = vc;
            *(uint4*)&Bs[1][br][c * 8] = vs;
        }
        __syncthreads();

        // ---- compute: 2 K=32 sub-steps, 8 MFMA each per wave
        #pragma unroll
        for (int ks = 0; ks < 2; ks++) {
            short8 a[2], bc[2], bsn[2];
            #pragma unroll
            for (int mf = 0; mf < 2; mf++) {
                int r = wid * 32 + mf * 16 + lrow;
                int c = (ks * 4 + lhi) ^ (r & 7);
                a[mf] = *(const short8*)&As[r][c * 8];
            }
            #pragma unroll
            for (int nf = 0; nf < 2; nf++) {
                int r = nf * 16 + lrow;
                int c = (ks * 4 + lhi) ^ (r & 7);
                bc[nf]  = *(const short8*)&Bs[0][r][c * 8];
                bsn[nf] = *(const short8*)&Bs[1][r][c * 8];
            }
            #pragma unroll
            for (int mf = 0; mf < 2; mf++) {
                #pragma unroll
                for (int nf = 0; nf < 2; nf++) {
                    accr[mf][nf] = __builtin_amdgcn_mfma_f32_16x16x32_bf16(
                        a[mf], bc[nf], accr[mf][nf], 0, 0, 0);
                    acci[mf][nf] = __builtin_amdgcn_mfma_f32_16x16x32_bf16(
                        a[mf], bsn[nf], acci[mf][nf], 0, 0, 0);
                }
            }
        }
    }

    // ---- epilogue: mag = sqrt(r^2 + i^2), float4 over 4 consecutive t
    #pragma unroll
    for (int mf = 0; mf < 2; mf++) {
        int m0 = tileM * MT + wid * 32 + mf * 16 + lhi * 4;
        int b = m0 / TFRAMES;
        int t = m0 - b * TFRAMES;               // multiple of 4; 4-run stays in batch
        #pragma unroll
        for (int nf = 0; nf < 2; nf++) {
            int f = tileF * FT + nf * 16 + lrow;
            if (f < NFREQ) {
                float4 o;
                o.x = sqrtf(accr[mf][nf][0] * accr[mf][nf][0] + acci[mf][nf][0] * acci[mf][nf][0]);
                o.y = sqrtf(accr[mf][nf][1] * accr[mf][nf][1] + acci[mf][nf][1] * acci[mf][nf][1]);
                o.z = sqrtf(accr[mf][nf][2] * accr[mf][nf][2] + acci[mf][nf][2] * acci[mf][nf][2]);
                o.w = sqrtf(accr[mf][nf][3] * accr[mf][nf][3] + acci[mf][nf][3] * acci[mf][nf][3]);
                *(float4*)(mag + ((size_t)b * NFREQ + f) * TFRAMES + t) = o;
            }
        }
    }
}

// ------------------------------------------------------------- normalize ----
__global__ __launch_bounds__(256) void normalize(const float* __restrict__ mag,
                                                 float* __restrict__ feat)
{
    __shared__ float red[8];
    const int row = blockIdx.x;                 // b*NFREQ + f
    const float* m = mag + (size_t)row * TFRAMES;
    const int tid = threadIdx.x;
    const int lane = tid & 63;
    const int w = tid >> 6;

    float v[3];
    float sum = 0.f;
    #pragma unroll
    for (int i = 0; i < 3; i++) {
        int t = tid + i * 256;
        v[i] = (t < TFRAMES) ? fmaxf(m[t], EPS) : 0.f;
        sum += v[i];
    }
    #pragma unroll
    for (int off = 32; off > 0; off >>= 1) sum += __shfl_down(sum, off, 64);
    if (lane == 0) red[w] = sum;
    __syncthreads();
    float total = red[0] + red[1] + red[2] + red[3];
    float mean = total * (1.0f / (float)TFRAMES);

    float ssd = 0.f;
    #pragma unroll
    for (int i = 0; i < 3; i++) {
        int t = tid + i * 256;
        if (t < TFRAMES) { float d = v[i] - mean; ssd += d * d; }
    }
    __syncthreads();
    #pragma unroll
    for (int off = 32; off > 0; off >>= 1) ssd += __shfl_down(ssd, off, 64);
    if (lane == 0) red[w] = ssd;
    __syncthreads();
    float tssd = red[0] + red[1] + red[2] + red[3];
    float stdv = sqrtf(tssd * (1.0f / (float)(TFRAMES - 1)));
    float inv = 1.0f / (stdv + EPS);

    #pragma unroll
    for (int i = 0; i < 3; i++) {
        int t = tid + i * 256;
        if (t < TFRAMES) feat[(size_t)row * TFRAMES + t] = (v[i] - mean) * inv;
    }
}

// ---------------------------------------------------------------- launch ----
extern "C" void kernel_launch(void* const* d_in, const int* in_sizes, int n_in,
                              void* d_out, int out_size, void* d_ws, size_t ws_size,
                              hipStream_t stream) {
    const float* x = (const float*)d_in[0];
    unsigned short* Wc = (unsigned short*)d_ws;             // 288*512 bf16
    unsigned short* Ws = Wc + NFREQ_PAD * FRAME_LEN;        // 288*512 bf16
    float* mag = (float*)d_out;                             // [64][257][624]
    float* feat = mag + (size_t)NBATCH * NFREQ * TFRAMES;

    gen_tables<<<NFREQ_PAD, 256, 0, stream>>>(Wc, Ws);

    dim3 grid2(NBATCH * TFRAMES / MT, NFREQ_PAD / FT);      // 312 x 9
    stft_mfma<<<grid2, 256, 0, stream>>>(x, Wc, Ws, mag);

    normalize<<<NBATCH * NFREQ, 256, 0, stream>>>(mag, feat);
}

// Round 3
// 93.167 us; speedup vs baseline: 7.3481x; 1.0280x over previous
//
#include <hip/hip_runtime.h>
#include <math.h>

#define FRAME_LEN 512
#define HOP       256
#define NFREQ     257
#define NFREQ_PAD 288
#define NBATCH    64
#define NSAMP     160000
#define TFRAMES   624
#define EPS       1.1920928955078125e-07f

#define MT 256                 // frames per tile
#define FT 32                  // freq bins per tile
#define BK 64                  // K chunk per stage

typedef __attribute__((ext_vector_type(8))) short short8;   // 8 bf16
typedef __attribute__((ext_vector_type(4))) float f32x4;    // MFMA acc

static __device__ __forceinline__ unsigned int f2bf(float f) {
    unsigned int u = __float_as_uint(f);
    return (u + 0x7fffu + ((u >> 16) & 1u)) >> 16;          // RNE to bf16
}
static __device__ __forceinline__ uint4 pack8(float4 a, float4 b) {
    uint4 r;
    r.x = f2bf(a.x) | (f2bf(a.y) << 16);
    r.y = f2bf(a.z) | (f2bf(a.w) << 16);
    r.z = f2bf(b.x) | (f2bf(b.y) << 16);
    r.w = f2bf(b.z) | (f2bf(b.w) << 16);
    return r;
}
static __device__ __forceinline__ void gload_lds16(const void* g, void* l) {
    __builtin_amdgcn_global_load_lds(
        (const __attribute__((address_space(1))) void*)g,
        (__attribute__((address_space(3))) void*)l, 16, 0, 0);
}

// ---------------------------------------------------------------- tables ----
__global__ void gen_tables(unsigned short* __restrict__ Wc,
                           unsigned short* __restrict__ Ws) {
    int f = blockIdx.x;                         // 0..287
    for (int n = threadIdx.x; n < FRAME_LEN; n += 256) {
        unsigned short c = 0, s = 0;
        if (f < NFREQ) {
            float w = 0.5f * (1.0f - cosf(2.0f * (float)M_PI * (float)n / (float)FRAME_LEN));
            int r = (f * n) & (FRAME_LEN - 1);
            float ang = (float)r * (2.0f * (float)M_PI / (float)FRAME_LEN);
            float sv, cv;
            sincosf(ang, &sv, &cv);
            c = (unsigned short)f2bf(cv * w);
            s = (unsigned short)f2bf(sv * w);   // i = +sin*w
        }
        Wc[f * FRAME_LEN + n] = c;
        Ws[f * FRAME_LEN + n] = s;
    }
}

// ---------------------------------------------------------------- prepass ---
__global__ __launch_bounds__(256) void x_to_bf16(const float* __restrict__ x,
                                                 unsigned short* __restrict__ xbf) {
    int i = blockIdx.x * 256 + threadIdx.x;     // 8 elems per thread
    const float4* src = (const float4*)x + (size_t)i * 2;
    float4 a = src[0], b = src[1];
    *(uint4*)(xbf + (size_t)i * 8) = pack8(a, b);
}

// ------------------------------------------------------ stft via bf16 MFMA --
__global__ __launch_bounds__(256) void stft_mfma(
    const unsigned short* __restrict__ xbf, const unsigned short* __restrict__ Wc,
    const unsigned short* __restrict__ Ws, float* __restrict__ mag)
{
    __shared__ unsigned short As[MT][BK];       // 32 KB, linear (gload_lds dest)
    __shared__ unsigned short Bs[2][FT][BK];    // 8 KB (cos, sin)

    const int tid = threadIdx.x;
    const int tileF = blockIdx.x;               // 0..8   (f inner for A reuse)
    const int tileM = blockIdx.y;               // 0..155
    const int wid = tid >> 6;
    const int lane = tid & 63;
    const int lrow = lane & 15;
    const int lhi = lane >> 4;

    // k0-invariant per-lane staging sources (swizzle applied to SOURCE chunk)
    const unsigned short* pA[8];
    #pragma unroll
    for (int j = 0; j < 8; j++) {
        int idx = wid * 8 + j;                  // 0..31, 8 rows each
        int row = idx * 8 + (lane >> 3);
        int m = tileM * MT + row;
        int b = m / TFRAMES;
        int t = m - b * TFRAMES;
        int chunk = (lane & 7) ^ (row & 7);
        pA[j] = xbf + (size_t)b * NSAMP + t * HOP + chunk * 8;
    }
    const unsigned short* pB[2];
    #pragma unroll
    for (int j = 0; j < 2; j++) {
        int i = wid * 2 + j;                    // 0..7: 0-3 cos, 4-7 sin
        int row = (i & 3) * 8 + (lane >> 3);
        int f = tileF * FT + row;               // < 288
        int chunk = (lane & 7) ^ (row & 7);
        const unsigned short* tbl = (i & 4) ? Ws : Wc;
        pB[j] = tbl + f * FRAME_LEN + chunk * 8;
    }

    f32x4 accr[4][2] = {};
    f32x4 acci[4][2] = {};

    for (int k0 = 0; k0 < FRAME_LEN; k0 += BK) {
        __syncthreads();                        // previous reads done
        #pragma unroll
        for (int j = 0; j < 8; j++)
            gload_lds16(pA[j] + k0, (unsigned short*)As + (wid * 8 + j) * 512);
        #pragma unroll
        for (int j = 0; j < 2; j++)
            gload_lds16(pB[j] + k0, (unsigned short*)Bs + (wid * 2 + j) * 512);
        __syncthreads();                        // vmcnt drained by compiler

        #pragma unroll
        for (int ks = 0; ks < 2; ks++) {
            short8 a[4], bc[2], bsn[2];
            const int c = (ks * 4 + lhi) ^ (lrow & 7);
            #pragma unroll
            for (int mf = 0; mf < 4; mf++)
                a[mf] = *(const short8*)&As[wid * 64 + mf * 16 + lrow][c * 8];
            #pragma unroll
            for (int nf = 0; nf < 2; nf++) {
                bc[nf]  = *(const short8*)&Bs[0][nf * 16 + lrow][c * 8];
                bsn[nf] = *(const short8*)&Bs[1][nf * 16 + lrow][c * 8];
            }
            #pragma unroll
            for (int mf = 0; mf < 4; mf++) {
                #pragma unroll
                for (int nf = 0; nf < 2; nf++) {
                    accr[mf][nf] = __builtin_amdgcn_mfma_f32_16x16x32_bf16(
                        a[mf], bc[nf], accr[mf][nf], 0, 0, 0);
                    acci[mf][nf] = __builtin_amdgcn_mfma_f32_16x16x32_bf16(
                        a[mf], bsn[nf], acci[mf][nf], 0, 0, 0);
                }
            }
        }
    }

    // ---- epilogue: mag = sqrt(r^2 + i^2), float4 over 4 consecutive t
    #pragma unroll
    for (int mf = 0; mf < 4; mf++) {
        int m0 = tileM * MT + wid * 64 + mf * 16 + lhi * 4;
        int b = m0 / TFRAMES;
        int t = m0 - b * TFRAMES;               // %4==0, run stays in batch
        #pragma unroll
        for (int nf = 0; nf < 2; nf++) {
            int f = tileF * FT + nf * 16 + lrow;
            if (f < NFREQ) {
                float4 o;
                o.x = sqrtf(accr[mf][nf][0] * accr[mf][nf][0] + acci[mf][nf][0] * acci[mf][nf][0]);
                o.y = sqrtf(accr[mf][nf][1] * accr[mf][nf][1] + acci[mf][nf][1] * acci[mf][nf][1]);
                o.z = sqrtf(accr[mf][nf][2] * accr[mf][nf][2] + acci[mf][nf][2] * acci[mf][nf][2]);
                o.w = sqrtf(accr[mf][nf][3] * accr[mf][nf][3] + acci[mf][nf][3] * acci[mf][nf][3]);
                *(float4*)(mag + ((size_t)b * NFREQ + f) * TFRAMES + t) = o;
            }
        }
    }
}

// ------------------------------------------- normalize: warp-per-row, f4 ----
__global__ __launch_bounds__(256) void normalize(const float* __restrict__ mag,
                                                 float* __restrict__ feat)
{
    const int row = blockIdx.x * 4 + (threadIdx.x >> 6);    // b*NFREQ+f
    const int lane = threadIdx.x & 63;
    const float* mp = mag + (size_t)row * TFRAMES;

    float4 v[3];
    float sum = 0.f;
    #pragma unroll
    for (int i = 0; i < 3; i++) {
        int c4 = lane + i * 64;                 // 156 float4 per row
        if (c4 < TFRAMES / 4) {
            float4 t = *(const float4*)(mp + c4 * 4);
            t.x = fmaxf(t.x, EPS); t.y = fmaxf(t.y, EPS);
            t.z = fmaxf(t.z, EPS); t.w = fmaxf(t.w, EPS);
            v[i] = t;
            sum += (t.x + t.y) + (t.z + t.w);
        } else {
            v[i] = make_float4(0.f, 0.f, 0.f, 0.f);
        }
    }
    #pragma unroll
    for (int off = 1; off < 64; off <<= 1) sum += __shfl_xor(sum, off, 64);
    const float mean = sum * (1.0f / (float)TFRAMES);

    float ssd = 0.f;
    #pragma unroll
    for (int i = 0; i < 3; i++) {
        int c4 = lane + i * 64;
        if (c4 < TFRAMES / 4) {
            float dx = v[i].x - mean, dy = v[i].y - mean;
            float dz = v[i].z - mean, dw = v[i].w - mean;
            ssd += (dx * dx + dy * dy) + (dz * dz + dw * dw);
        }
    }
    #pragma unroll
    for (int off = 1; off < 64; off <<= 1) ssd += __shfl_xor(ssd, off, 64);
    const float stdv = sqrtf(ssd * (1.0f / (float)(TFRAMES - 1)));
    const float inv = 1.0f / (stdv + EPS);

    float* fp = feat + (size_t)row * TFRAMES;
    #pragma unroll
    for (int i = 0; i < 3; i++) {
        int c4 = lane + i * 64;
        if (c4 < TFRAMES / 4) {
            float4 o;
            o.x = (v[i].x - mean) * inv; o.y = (v[i].y - mean) * inv;
            o.z = (v[i].z - mean) * inv; o.w = (v[i].w - mean) * inv;
            *(float4*)(fp + c4 * 4) = o;
        }
    }
}

// ---------------------------------------------------------------- launch ----
extern "C" void kernel_launch(void* const* d_in, const int* in_sizes, int n_in,
                              void* d_out, int out_size, void* d_ws, size_t ws_size,
                              hipStream_t stream) {
    const float* x = (const float*)d_in[0];
    unsigned short* Wc  = (unsigned short*)d_ws;            // 288*512 bf16
    unsigned short* Ws  = Wc + NFREQ_PAD * FRAME_LEN;       // 288*512 bf16
    unsigned short* xbf = Ws + NFREQ_PAD * FRAME_LEN;       // 64*160000 bf16
    float* mag  = (float*)d_out;                            // [64][257][624]
    float* feat = mag + (size_t)NBATCH * NFREQ * TFRAMES;

    gen_tables<<<NFREQ_PAD, 256, 0, stream>>>(Wc, Ws);
    x_to_bf16<<<NBATCH * NSAMP / (256 * 8), 256, 0, stream>>>(x, xbf);

    dim3 grid2(NFREQ_PAD / FT, NBATCH * TFRAMES / MT);      // 9 x 156
    stft_mfma<<<grid2, 256, 0, stream>>>(xbf, Wc, Ws, mag);

    normalize<<<NBATCH * NFREQ / 4, 256, 0, stream>>>(mag, feat);
}

// Round 4
// 64.911 us; speedup vs baseline: 10.5467x; 1.4353x over previous
//
#include <hip/hip_runtime.h>
#include <math.h>

#define FRAME_LEN 512
#define HOP       256
#define NFREQ     257
#define NFREQ_PAD 288
#define NBATCH    64
#define NSAMP     160000
#define TFRAMES   624
#define EPS       1.1920928955078125e-07f

#define MT 128                 // frames per tile (24KB LDS -> 6 blocks/CU)
#define FT 32                  // freq bins per tile
#define BK 64                  // K chunk per stage
#define NXCD 8

typedef __attribute__((ext_vector_type(8))) short short8;   // 8 bf16
typedef __attribute__((ext_vector_type(4))) float f32x4;    // MFMA acc

static __device__ __forceinline__ unsigned int f2bf(float f) {
    unsigned int u = __float_as_uint(f);
    return (u + 0x7fffu + ((u >> 16) & 1u)) >> 16;          // RNE to bf16
}
static __device__ __forceinline__ uint4 pack8(float4 a, float4 b) {
    uint4 r;
    r.x = f2bf(a.x) | (f2bf(a.y) << 16);
    r.y = f2bf(a.z) | (f2bf(a.w) << 16);
    r.z = f2bf(b.x) | (f2bf(b.y) << 16);
    r.w = f2bf(b.z) | (f2bf(b.w) << 16);
    return r;
}
static __device__ __forceinline__ void gload_lds16(const void* g, void* l) {
    __builtin_amdgcn_global_load_lds(
        (const __attribute__((address_space(1))) void*)g,
        (__attribute__((address_space(3))) void*)l, 16, 0, 0);
}

// ---------------------------------------------------------------- tables ----
__global__ void gen_tables(unsigned short* __restrict__ Wc,
                           unsigned short* __restrict__ Ws) {
    int f = blockIdx.x;                         // 0..287
    for (int n = threadIdx.x; n < FRAME_LEN; n += 256) {
        unsigned short c = 0, s = 0;
        if (f < NFREQ) {
            float w = 0.5f * (1.0f - cosf(2.0f * (float)M_PI * (float)n / (float)FRAME_LEN));
            int r = (f * n) & (FRAME_LEN - 1);
            float ang = (float)r * (2.0f * (float)M_PI / (float)FRAME_LEN);
            float sv, cv;
            sincosf(ang, &sv, &cv);
            c = (unsigned short)f2bf(cv * w);
            s = (unsigned short)f2bf(sv * w);   // i = +sin*w
        }
        Wc[f * FRAME_LEN + n] = c;
        Ws[f * FRAME_LEN + n] = s;
    }
}

// ---------------------------------------------------------------- prepass ---
__global__ __launch_bounds__(256) void x_to_bf16(const float* __restrict__ x,
                                                 unsigned short* __restrict__ xbf) {
    int i = blockIdx.x * 256 + threadIdx.x;     // 8 elems per thread
    const float4* src = (const float4*)x + (size_t)i * 2;
    float4 a = src[0], b = src[1];
    *(uint4*)(xbf + (size_t)i * 8) = pack8(a, b);
}

// ------------------------------------------------------ stft via bf16 MFMA --
__global__ __launch_bounds__(256) void stft_mfma(
    const unsigned short* __restrict__ xbf, const unsigned short* __restrict__ Wc,
    const unsigned short* __restrict__ Ws, float* __restrict__ mag)
{
    __shared__ unsigned short As[MT][BK];       // 16 KB, linear (gload_lds dest)
    __shared__ unsigned short Bs[2][FT][BK];    // 8 KB (cos, sin)

    const int tid = threadIdx.x;
    // Bijective XCD swizzle (m204): nwg=2808=8*351; consecutive logical ids
    // land on one XCD so the 9 f-tiles sharing an A-tile hit the same L2.
    const int logical = (blockIdx.x % NXCD) * (2808 / NXCD) + blockIdx.x / NXCD;
    const int tileM = logical / 9;              // 0..311
    const int tileF = logical % 9;              // 0..8
    const int wid = tid >> 6;
    const int lane = tid & 63;
    const int lrow = lane & 15;
    const int lhi = lane >> 4;

    // k0-invariant per-lane staging sources (XOR swizzle on SOURCE chunk)
    const unsigned short* pA[4];
    #pragma unroll
    for (int j = 0; j < 4; j++) {
        int idx = wid * 4 + j;                  // 0..15, 8 rows each
        int row = idx * 8 + (lane >> 3);
        int m = tileM * MT + row;
        int b = m / TFRAMES;
        int t = m - b * TFRAMES;
        int chunk = (lane & 7) ^ (row & 7);
        pA[j] = xbf + (size_t)b * NSAMP + t * HOP + chunk * 8;
    }
    const unsigned short* pB[2];
    #pragma unroll
    for (int j = 0; j < 2; j++) {
        int i = wid * 2 + j;                    // 0..7: 0-3 cos, 4-7 sin
        int row = (i & 3) * 8 + (lane >> 3);
        int f = tileF * FT + row;               // < 288
        int chunk = (lane & 7) ^ (row & 7);
        const unsigned short* tbl = (i & 4) ? Ws : Wc;
        pB[j] = tbl + f * FRAME_LEN + chunk * 8;
    }

    f32x4 accr[2][2] = {};
    f32x4 acci[2][2] = {};

    for (int k0 = 0; k0 < FRAME_LEN; k0 += BK) {
        __syncthreads();                        // previous reads done
        #pragma unroll
        for (int j = 0; j < 4; j++)
            gload_lds16(pA[j] + k0, (unsigned short*)As + (wid * 4 + j) * 512);
        #pragma unroll
        for (int j = 0; j < 2; j++)
            gload_lds16(pB[j] + k0, (unsigned short*)Bs + (wid * 2 + j) * 512);
        __syncthreads();                        // vmcnt drained by compiler

        #pragma unroll
        for (int ks = 0; ks < 2; ks++) {
            short8 a[2], bc[2], bsn[2];
            const int c = (ks * 4 + lhi) ^ (lrow & 7);
            #pragma unroll
            for (int mf = 0; mf < 2; mf++)
                a[mf] = *(const short8*)&As[wid * 32 + mf * 16 + lrow][c * 8];
            #pragma unroll
            for (int nf = 0; nf < 2; nf++) {
                bc[nf]  = *(const short8*)&Bs[0][nf * 16 + lrow][c * 8];
                bsn[nf] = *(const short8*)&Bs[1][nf * 16 + lrow][c * 8];
            }
            #pragma unroll
            for (int mf = 0; mf < 2; mf++) {
                #pragma unroll
                for (int nf = 0; nf < 2; nf++) {
                    accr[mf][nf] = __builtin_amdgcn_mfma_f32_16x16x32_bf16(
                        a[mf], bc[nf], accr[mf][nf], 0, 0, 0);
                    acci[mf][nf] = __builtin_amdgcn_mfma_f32_16x16x32_bf16(
                        a[mf], bsn[nf], acci[mf][nf], 0, 0, 0);
                }
            }
        }
    }

    // ---- epilogue: mag = sqrt(r^2 + i^2), float4 over 4 consecutive t
    #pragma unroll
    for (int mf = 0; mf < 2; mf++) {
        int m0 = tileM * MT + wid * 32 + mf * 16 + lhi * 4;
        int b = m0 / TFRAMES;
        int t = m0 - b * TFRAMES;               // %4==0, run stays in batch
        #pragma unroll
        for (int nf = 0; nf < 2; nf++) {
            int f = tileF * FT + nf * 16 + lrow;
            if (f < NFREQ) {
                float4 o;
                o.x = sqrtf(accr[mf][nf][0] * accr[mf][nf][0] + acci[mf][nf][0] * acci[mf][nf][0]);
                o.y = sqrtf(accr[mf][nf][1] * accr[mf][nf][1] + acci[mf][nf][1] * acci[mf][nf][1]);
                o.z = sqrtf(accr[mf][nf][2] * accr[mf][nf][2] + acci[mf][nf][2] * acci[mf][nf][2]);
                o.w = sqrtf(accr[mf][nf][3] * accr[mf][nf][3] + acci[mf][nf][3] * acci[mf][nf][3]);
                *(float4*)(mag + ((size_t)b * NFREQ + f) * TFRAMES + t) = o;
            }
        }
    }
}

// ------------------------------------------- normalize: warp-per-row, f4 ----
__global__ __launch_bounds__(256) void normalize(const float* __restrict__ mag,
                                                 float* __restrict__ feat)
{
    const int row = blockIdx.x * 4 + (threadIdx.x >> 6);    // b*NFREQ+f
    const int lane = threadIdx.x & 63;
    const float* mp = mag + (size_t)row * TFRAMES;

    float4 v[3];
    float sum = 0.f;
    #pragma unroll
    for (int i = 0; i < 3; i++) {
        int c4 = lane + i * 64;                 // 156 float4 per row
        if (c4 < TFRAMES / 4) {
            float4 t = *(const float4*)(mp + c4 * 4);
            t.x = fmaxf(t.x, EPS); t.y = fmaxf(t.y, EPS);
            t.z = fmaxf(t.z, EPS); t.w = fmaxf(t.w, EPS);
            v[i] = t;
            sum += (t.x + t.y) + (t.z + t.w);
        } else {
            v[i] = make_float4(0.f, 0.f, 0.f, 0.f);
        }
    }
    #pragma unroll
    for (int off = 1; off < 64; off <<= 1) sum += __shfl_xor(sum, off, 64);
    const float mean = sum * (1.0f / (float)TFRAMES);

    float ssd = 0.f;
    #pragma unroll
    for (int i = 0; i < 3; i++) {
        int c4 = lane + i * 64;
        if (c4 < TFRAMES / 4) {
            float dx = v[i].x - mean, dy = v[i].y - mean;
            float dz = v[i].z - mean, dw = v[i].w - mean;
            ssd += (dx * dx + dy * dy) + (dz * dz + dw * dw);
        }
    }
    #pragma unroll
    for (int off = 1; off < 64; off <<= 1) ssd += __shfl_xor(ssd, off, 64);
    const float stdv = sqrtf(ssd * (1.0f / (float)(TFRAMES - 1)));
    const float inv = 1.0f / (stdv + EPS);

    float* fp = feat + (size_t)row * TFRAMES;
    #pragma unroll
    for (int i = 0; i < 3; i++) {
        int c4 = lane + i * 64;
        if (c4 < TFRAMES / 4) {
            float4 o;
            o.x = (v[i].x - mean) * inv; o.y = (v[i].y - mean) * inv;
            o.z = (v[i].z - mean) * inv; o.w = (v[i].w - mean) * inv;
            *(float4*)(fp + c4 * 4) = o;
        }
    }
}

// ---------------------------------------------------------------- launch ----
extern "C" void kernel_launch(void* const* d_in, const int* in_sizes, int n_in,
                              void* d_out, int out_size, void* d_ws, size_t ws_size,
                              hipStream_t stream) {
    const float* x = (const float*)d_in[0];
    unsigned short* Wc  = (unsigned short*)d_ws;            // 288*512 bf16
    unsigned short* Ws  = Wc + NFREQ_PAD * FRAME_LEN;       // 288*512 bf16
    unsigned short* xbf = Ws + NFREQ_PAD * FRAME_LEN;       // 64*160000 bf16
    float* mag  = (float*)d_out;                            // [64][257][624]
    float* feat = mag + (size_t)NBATCH * NFREQ * TFRAMES;

    gen_tables<<<NFREQ_PAD, 256, 0, stream>>>(Wc, Ws);
    x_to_bf16<<<NBATCH * NSAMP / (256 * 8), 256, 0, stream>>>(x, xbf);

    // 312 M-tiles x 9 F-tiles, linearized + XCD-swizzled in-kernel
    stft_mfma<<<312 * 9, 256, 0, stream>>>(xbf, Wc, Ws, mag);

    normalize<<<NBATCH * NFREQ / 4, 256, 0, stream>>>(mag, feat);
}

// Round 5
// 61.493 us; speedup vs baseline: 11.1329x; 1.0556x over previous
//
#include <hip/hip_runtime.h>
#include <math.h>

#define FRAME_LEN 512
#define HOP       256
#define NFREQ     257
#define NFREQ_PAD 288
#define NBATCH    64
#define NSAMP     160000
#define TFRAMES   624
#define EPS       1.1920928955078125e-07f

#define MT 128                 // frames per tile
#define FT 32                  // freq bins per tile
#define BK 64                  // K chunk per stage
#define NK (FRAME_LEN / BK)    // 8 K-iterations
#define NXCD 8
#define XBLKS 5000             // x-convert blocks in prep kernel

typedef __attribute__((ext_vector_type(8))) short short8;   // 8 bf16
typedef __attribute__((ext_vector_type(4))) float f32x4;    // MFMA acc

static __device__ __forceinline__ unsigned int f2bf(float f) {
    unsigned int u = __float_as_uint(f);
    return (u + 0x7fffu + ((u >> 16) & 1u)) >> 16;          // RNE to bf16
}
static __device__ __forceinline__ uint4 pack8(float4 a, float4 b) {
    uint4 r;
    r.x = f2bf(a.x) | (f2bf(a.y) << 16);
    r.y = f2bf(a.z) | (f2bf(a.w) << 16);
    r.z = f2bf(b.x) | (f2bf(b.y) << 16);
    r.w = f2bf(b.z) | (f2bf(b.w) << 16);
    return r;
}
static __device__ __forceinline__ void gload_lds16(const void* g, void* l) {
    __builtin_amdgcn_global_load_lds(
        (const __attribute__((address_space(1))) void*)g,
        (__attribute__((address_space(3))) void*)l, 16, 0, 0);
}

// ------------------------------------------------- prep: tables + x->bf16 ---
__global__ __launch_bounds__(256) void prep(const float* __restrict__ x,
                                            unsigned short* __restrict__ xbf,
                                            unsigned short* __restrict__ Wc,
                                            unsigned short* __restrict__ Ws) {
    if (blockIdx.x < XBLKS) {                   // x -> bf16, 8 elems/thread
        int i = blockIdx.x * 256 + threadIdx.x;
        const float4* src = (const float4*)x + (size_t)i * 2;
        float4 a = src[0], b = src[1];
        *(uint4*)(xbf + (size_t)i * 8) = pack8(a, b);
    } else {                                    // DFT tables, bf16, 288 rows
        int f = blockIdx.x - XBLKS;             // 0..287
        for (int n = threadIdx.x; n < FRAME_LEN; n += 256) {
            unsigned short c = 0, s = 0;
            if (f < NFREQ) {
                float w = 0.5f * (1.0f - cosf(2.0f * (float)M_PI * (float)n / (float)FRAME_LEN));
                int r = (f * n) & (FRAME_LEN - 1);
                float ang = (float)r * (2.0f * (float)M_PI / (float)FRAME_LEN);
                float sv, cv;
                sincosf(ang, &sv, &cv);
                c = (unsigned short)f2bf(cv * w);
                s = (unsigned short)f2bf(sv * w);   // i = +sin*w
            }
            Wc[f * FRAME_LEN + n] = c;
            Ws[f * FRAME_LEN + n] = s;
        }
    }
}

// --------------------------------- stft via bf16 MFMA, 2-phase LDS dbuf -----
__global__ __launch_bounds__(256) void stft_mfma(
    const unsigned short* __restrict__ xbf, const unsigned short* __restrict__ Wc,
    const unsigned short* __restrict__ Ws, float* __restrict__ mag)
{
    __shared__ unsigned short As[2][MT][BK];    // 2 x 16 KB, linear dest
    __shared__ unsigned short Bs[2][2][FT][BK]; // 2 x 8 KB (cos, sin)

    const int tid = threadIdx.x;
    // Bijective XCD swizzle: nwg=2808=8*351; 9 consecutive logical ids
    // (same A-tile) land on one XCD -> A fetched once per XCD L2.
    const int logical = (blockIdx.x % NXCD) * (2808 / NXCD) + blockIdx.x / NXCD;
    const int tileM = logical / 9;              // 0..311
    const int tileF = logical % 9;              // 0..8
    const int wid = tid >> 6;
    const int lane = tid & 63;
    const int lrow = lane & 15;
    const int lhi = lane >> 4;

    // k0-invariant per-lane staging sources (XOR swizzle on SOURCE chunk)
    const unsigned short* pA[4];
    #pragma unroll
    for (int j = 0; j < 4; j++) {
        int idx = wid * 4 + j;                  // 0..15, 8 rows each
        int row = idx * 8 + (lane >> 3);
        int m = tileM * MT + row;
        int b = m / TFRAMES;
        int t = m - b * TFRAMES;
        int chunk = (lane & 7) ^ (row & 7);
        pA[j] = xbf + (size_t)b * NSAMP + t * HOP + chunk * 8;
    }
    const unsigned short* pB[2];
    #pragma unroll
    for (int j = 0; j < 2; j++) {
        int i = wid * 2 + j;                    // 0..7: 0-3 cos, 4-7 sin
        int row = (i & 3) * 8 + (lane >> 3);
        int f = tileF * FT + row;               // < 288
        int chunk = (lane & 7) ^ (row & 7);
        const unsigned short* tbl = (i & 4) ? Ws : Wc;
        pB[j] = tbl + f * FRAME_LEN + chunk * 8;
    }

    f32x4 accr[2][2] = {};
    f32x4 acci[2][2] = {};

    // ---- prologue: stage k0=0 into buf 0, drain
    #pragma unroll
    for (int j = 0; j < 4; j++)
        gload_lds16(pA[j], (unsigned short*)As[0] + (wid * 4 + j) * 512);
    #pragma unroll
    for (int j = 0; j < 2; j++)
        gload_lds16(pB[j], (unsigned short*)Bs[0] + (wid * 2 + j) * 512);
    __syncthreads();

    for (int it = 0; it < NK; it++) {
        const int cur = it & 1;
        // ---- issue next-tile loads into other buffer (overlap with compute)
        if (it < NK - 1) {
            const int k0 = (it + 1) * BK;
            #pragma unroll
            for (int j = 0; j < 4; j++)
                gload_lds16(pA[j] + k0, (unsigned short*)As[cur ^ 1] + (wid * 4 + j) * 512);
            #pragma unroll
            for (int j = 0; j < 2; j++)
                gload_lds16(pB[j] + k0, (unsigned short*)Bs[cur ^ 1] + (wid * 2 + j) * 512);
        }
        // ---- compute current buffer
        #pragma unroll
        for (int ks = 0; ks < 2; ks++) {
            short8 a[2], bc[2], bsn[2];
            const int c = (ks * 4 + lhi) ^ (lrow & 7);
            #pragma unroll
            for (int mf = 0; mf < 2; mf++)
                a[mf] = *(const short8*)&As[cur][wid * 32 + mf * 16 + lrow][c * 8];
            #pragma unroll
            for (int nf = 0; nf < 2; nf++) {
                bc[nf]  = *(const short8*)&Bs[cur][0][nf * 16 + lrow][c * 8];
                bsn[nf] = *(const short8*)&Bs[cur][1][nf * 16 + lrow][c * 8];
            }
            #pragma unroll
            for (int mf = 0; mf < 2; mf++) {
                #pragma unroll
                for (int nf = 0; nf < 2; nf++) {
                    accr[mf][nf] = __builtin_amdgcn_mfma_f32_16x16x32_bf16(
                        a[mf], bc[nf], accr[mf][nf], 0, 0, 0);
                    acci[mf][nf] = __builtin_amdgcn_mfma_f32_16x16x32_bf16(
                        a[mf], bsn[nf], acci[mf][nf], 0, 0, 0);
                }
            }
        }
        __syncthreads();   // next buffer's loads landed; prior reads done
    }

    // ---- epilogue: mag = sqrt(r^2 + i^2), float4 over 4 consecutive t
    #pragma unroll
    for (int mf = 0; mf < 2; mf++) {
        int m0 = tileM * MT + wid * 32 + mf * 16 + lhi * 4;
        int b = m0 / TFRAMES;
        int t = m0 - b * TFRAMES;               // %4==0, run stays in batch
        #pragma unroll
        for (int nf = 0; nf < 2; nf++) {
            int f = tileF * FT + nf * 16 + lrow;
            if (f < NFREQ) {
                float4 o;
                o.x = sqrtf(accr[mf][nf][0] * accr[mf][nf][0] + acci[mf][nf][0] * acci[mf][nf][0]);
                o.y = sqrtf(accr[mf][nf][1] * accr[mf][nf][1] + acci[mf][nf][1] * acci[mf][nf][1]);
                o.z = sqrtf(accr[mf][nf][2] * accr[mf][nf][2] + acci[mf][nf][2] * acci[mf][nf][2]);
                o.w = sqrtf(accr[mf][nf][3] * accr[mf][nf][3] + acci[mf][nf][3] * acci[mf][nf][3]);
                *(float4*)(mag + ((size_t)b * NFREQ + f) * TFRAMES + t) = o;
            }
        }
    }
}

// ------------------------------------------- normalize: warp-per-row, f4 ----
__global__ __launch_bounds__(256) void normalize(const float* __restrict__ mag,
                                                 float* __restrict__ feat)
{
    const int row = blockIdx.x * 4 + (threadIdx.x >> 6);    // b*NFREQ+f
    const int lane = threadIdx.x & 63;
    const float* mp = mag + (size_t)row * TFRAMES;

    float4 v[3];
    float sum = 0.f;
    #pragma unroll
    for (int i = 0; i < 3; i++) {
        int c4 = lane + i * 64;                 // 156 float4 per row
        if (c4 < TFRAMES / 4) {
            float4 t = *(const float4*)(mp + c4 * 4);
            t.x = fmaxf(t.x, EPS); t.y = fmaxf(t.y, EPS);
            t.z = fmaxf(t.z, EPS); t.w = fmaxf(t.w, EPS);
            v[i] = t;
            sum += (t.x + t.y) + (t.z + t.w);
        } else {
            v[i] = make_float4(0.f, 0.f, 0.f, 0.f);
        }
    }
    #pragma unroll
    for (int off = 1; off < 64; off <<= 1) sum += __shfl_xor(sum, off, 64);
    const float mean = sum * (1.0f / (float)TFRAMES);

    float ssd = 0.f;
    #pragma unroll
    for (int i = 0; i < 3; i++) {
        int c4 = lane + i * 64;
        if (c4 < TFRAMES / 4) {
            float dx = v[i].x - mean, dy = v[i].y - mean;
            float dz = v[i].z - mean, dw = v[i].w - mean;
            ssd += (dx * dx + dy * dy) + (dz * dz + dw * dw);
        }
    }
    #pragma unroll
    for (int off = 1; off < 64; off <<= 1) ssd += __shfl_xor(ssd, off, 64);
    const float stdv = sqrtf(ssd * (1.0f / (float)(TFRAMES - 1)));
    const float inv = 1.0f / (stdv + EPS);

    float* fp = feat + (size_t)row * TFRAMES;
    #pragma unroll
    for (int i = 0; i < 3; i++) {
        int c4 = lane + i * 64;
        if (c4 < TFRAMES / 4) {
            float4 o;
            o.x = (v[i].x - mean) * inv; o.y = (v[i].y - mean) * inv;
            o.z = (v[i].z - mean) * inv; o.w = (v[i].w - mean) * inv;
            *(float4*)(fp + c4 * 4) = o;
        }
    }
}

// ---------------------------------------------------------------- launch ----
extern "C" void kernel_launch(void* const* d_in, const int* in_sizes, int n_in,
                              void* d_out, int out_size, void* d_ws, size_t ws_size,
                              hipStream_t stream) {
    const float* x = (const float*)d_in[0];
    unsigned short* Wc  = (unsigned short*)d_ws;            // 288*512 bf16
    unsigned short* Ws  = Wc + NFREQ_PAD * FRAME_LEN;       // 288*512 bf16
    unsigned short* xbf = Ws + NFREQ_PAD * FRAME_LEN;       // 64*160000 bf16
    float* mag  = (float*)d_out;                            // [64][257][624]
    float* feat = mag + (size_t)NBATCH * NFREQ * TFRAMES;

    prep<<<XBLKS + NFREQ_PAD, 256, 0, stream>>>(x, xbf, Wc, Ws);

    // 312 M-tiles x 9 F-tiles, linearized + XCD-swizzled in-kernel
    stft_mfma<<<312 * 9, 256, 0, stream>>>(xbf, Wc, Ws, mag);

    normalize<<<NBATCH * NFREQ / 4, 256, 0, stream>>>(mag, feat);
}